// Round 19
// baseline (259.928 us; speedup 1.0000x reference)
//
#include <hip/hip_runtime.h>
#include <hip/hip_bf16.h>

// QuantiZ: e = codebook[4096,1024] @ proj_w[256,1024]^T + proj_b
//          zidx[t] = argmin_k ||z_t - e_k||, quant[t] = e[zidx[t]]
// d_out FLOAT32: [ zidx as float (32768) | quant (32768*256) ].
// Score GEMM: split-bf16 3-term (hi*hi + hi*lo + lo*hi), 16x16x32 MFMA.
// R19 = R18 re-split: waves = 4 token-groups x 2 code-groups (32 tok x 128
//       codes, i in 2, jj in 8). A ds_reads per CU per step halve (768->384
//       cyc); B distinct bytes unchanged (at floor). Depth-1 pipeline +
//       setprio fence retained.

#define K_CODES 4096
#define CDIM    256
#define IDIM    1024
#define NTOK    32768

typedef __attribute__((ext_vector_type(8))) short short8;
typedef __attribute__((ext_vector_type(4))) float f32x4;

__device__ __forceinline__ unsigned short f32_to_bf16_rne(float f) {
  union { float f; unsigned int u; } x; x.f = f;
  unsigned int r = x.u + 0x7FFFu + ((x.u >> 16) & 1u);
  return (unsigned short)(r >> 16);
}
__device__ __forceinline__ float bf16_to_f32(unsigned short h) {
  union { unsigned int u; float f; } x; x.u = ((unsigned int)h) << 16;
  return x.f;
}

// ---- Kernel A: e = cb @ pw^T + pb (f32 64x64 tile) + fused Ect split -------
extern "C" __global__ __launch_bounds__(256)
void proj_gemm(const float* __restrict__ cb, const float* __restrict__ pw,
               const float* __restrict__ pb, float* __restrict__ e,
               unsigned short* __restrict__ Ect) {
  __shared__ float As[32][68];   // [kk][row]
  __shared__ float Bs[32][68];
  const int tid = threadIdx.x;
  const int tx = tid & 15, ty = tid >> 4;
  const int m0 = blockIdx.y << 6;
  const int n0 = blockIdx.x << 6;
  const int r  = tid >> 2;
  const int c8 = (tid & 3) << 3;
  float acc[4][4] = {};
  for (int k0 = 0; k0 < IDIM; k0 += 32) {
    float4 a0 = *(const float4*)&cb[(m0 + r) * IDIM + k0 + c8];
    float4 a1 = *(const float4*)&cb[(m0 + r) * IDIM + k0 + c8 + 4];
    float4 b0 = *(const float4*)&pw[(n0 + r) * IDIM + k0 + c8];
    float4 b1 = *(const float4*)&pw[(n0 + r) * IDIM + k0 + c8 + 4];
    __syncthreads();
    As[c8+0][r]=a0.x; As[c8+1][r]=a0.y; As[c8+2][r]=a0.z; As[c8+3][r]=a0.w;
    As[c8+4][r]=a1.x; As[c8+5][r]=a1.y; As[c8+6][r]=a1.z; As[c8+7][r]=a1.w;
    Bs[c8+0][r]=b0.x; Bs[c8+1][r]=b0.y; Bs[c8+2][r]=b0.z; Bs[c8+3][r]=b0.w;
    Bs[c8+4][r]=b1.x; Bs[c8+5][r]=b1.y; Bs[c8+6][r]=b1.z; Bs[c8+7][r]=b1.w;
    __syncthreads();
    #pragma unroll
    for (int kk = 0; kk < 32; ++kk) {
      const float4 av = *(const float4*)&As[kk][ty*4];
      const float4 bv = *(const float4*)&Bs[kk][tx*4];
      const float a4[4] = {av.x, av.y, av.z, av.w};
      const float b4[4] = {bv.x, bv.y, bv.z, bv.w};
      #pragma unroll
      for (int i = 0; i < 4; ++i)
        #pragma unroll
        for (int j = 0; j < 4; ++j)
          acc[i][j] += a4[i] * b4[j];
    }
  }
  const int col0 = n0 + tx*4;
  const int kb   = col0 >> 5;
  const int g    = (col0 >> 3) & 3;
  const int half = (col0 >> 2) & 1;
  #pragma unroll
  for (int i = 0; i < 4; ++i) {
    const int row = m0 + ty*4 + i;
    float vv[4];
    unsigned short h4[4], l4[4];
    #pragma unroll
    for (int j = 0; j < 4; ++j) {
      vv[j] = acc[i][j] + pb[col0 + j];
      h4[j] = f32_to_bf16_rne(vv[j]);
      l4[j] = f32_to_bf16_rne(vv[j] - bf16_to_f32(h4[j]));
    }
    *(float4*)&e[(size_t)row * CDIM + col0] = *(float4*)vv;
    const int ct = row >> 4, cl = row & 15;
    const size_t fi = ((size_t)(kb      * 256 + ct) * 64 + g*16 + cl) * 8 + half*4;
    const size_t fo = ((size_t)((kb+8)  * 256 + ct) * 64 + g*16 + cl) * 8 + half*4;
    *(ushort4*)&Ect[fi] = *(ushort4*)h4;
    *(ushort4*)&Ect[fo] = *(ushort4*)l4;
  }
}

// ---------------- Kernel A3: e2[k] = sum_c e[k][c]^2 ------------------------
extern "C" __global__ __launch_bounds__(256)
void compute_e2(const float* __restrict__ e, float* __restrict__ e2) {
  const int gid  = blockIdx.x * 256 + threadIdx.x;
  const int w    = gid >> 6;
  const int lane = threadIdx.x & 63;
  float4 v = *(const float4*)&e[(size_t)w * CDIM + (lane << 2)];
  float s = v.x*v.x + v.y*v.y + v.z*v.z + v.w*v.w;
  #pragma unroll
  for (int off = 32; off > 0; off >>= 1) s += __shfl_down(s, off, 64);
  if (lane == 0) e2[w] = s;
}

// ---------------- Kernel B: MFMA score + argmin + fused gather --------------
// 128 tokens/block, 8 waves = 4 token-groups (tg) x 2 code-groups (cg).
// Wave = 32 tok x 128 codes (i in 2, jj in 8). Z: 128 frag-linear LDS frags.
// Waves sharing cg (4 of them) read identical B fragments (L1 reuse).
extern "C" __global__ __launch_bounds__(512, 2)
void score_mfma(const float* __restrict__ z, const unsigned short* __restrict__ Ect,
                const float* __restrict__ e2g, const float* __restrict__ eg,
                float* __restrict__ zidx_f, float* __restrict__ quant) {
  extern __shared__ __align__(16) char smem[];   // 128K Z + red + idx
  char* Zb = smem;

  const int tid = threadIdx.x;
  const int l   = tid & 63;
  const int w   = tid >> 6;          // wave 0..7
  const int tg  = w >> 1;            // token group 0..3
  const int cg  = w & 1;             // code group 0..1
  const int t0  = blockIdx.x << 7;   // 128 tokens per block

  // ---- stage Z (hi/lo bf16) into fragment-linear LDS frags ----
  #pragma unroll
  for (int rr = 0; rr < 2; ++rr) {
    const int r  = rr*64 + (tid >> 3);    // token row 0..127
    const int cq = tid & 7;               // col base cq*32
    const int i8 = r >> 4;                // frag i 0..7
    const int rl = (r & 15) << 4;         // lane-slot byte within frag
    #pragma unroll
    for (int it = 0; it < 4; ++it) {
      const int col = cq*32 + it*8;       // g = it, kb_hi = cq, kb_lo = cq+8
      const float4 v0 = *(const float4*)&z[(size_t)(t0 + r) * CDIM + col];
      const float4 v1 = *(const float4*)&z[(size_t)(t0 + r) * CDIM + col + 4];
      float vv[8] = {v0.x,v0.y,v0.z,v0.w,v1.x,v1.y,v1.z,v1.w};
      unsigned int hp[4], lp[4];
      #pragma unroll
      for (int c = 0; c < 4; ++c) {
        unsigned short h0 = f32_to_bf16_rne(vv[2*c]);
        unsigned short h1 = f32_to_bf16_rne(vv[2*c+1]);
        unsigned short l0 = f32_to_bf16_rne(vv[2*c]   - bf16_to_f32(h0));
        unsigned short l1 = f32_to_bf16_rne(vv[2*c+1] - bf16_to_f32(h1));
        hp[c] = (unsigned int)h0 | ((unsigned int)h1 << 16);
        lp[c] = (unsigned int)l0 | ((unsigned int)l1 << 16);
      }
      const int lane_b = it*256 + rl;     // (g*16 + (r&15)) * 16
      *(uint4*)(Zb + (size_t)(i8*16 + cq    ) * 1024 + lane_b) = *(uint4*)hp;
      *(uint4*)(Zb + (size_t)(i8*16 + cq + 8) * 1024 + lane_b) = *(uint4*)lp;
    }
  }
  __syncthreads();   // Z ready; no further barriers until final reduce

  float bestv[2][4];
  int   besti[2][4];
  #pragma unroll
  for (int i = 0; i < 2; ++i)
    #pragma unroll
    for (int r = 0; r < 4; ++r) { bestv[i][r] = 3.4e38f; besti[i][r] = 0; }

  const int cl = l & 15;
  const int g  = l >> 4;

  // Ect frag(kb, ct) at (kb*256+ct)*1024; wave's ct = cc*16 + cg*8 + jj
  const char* ebase = (const char*)Ect + (size_t)l * 16 + (size_t)cg * 8192;
  // A frags for this wave: frag index (tg*2 + i)*16 + kb
  const char* Zl    = Zb + (size_t)l * 16 + (size_t)tg * 32768;

  // pipeline registers (depth-1), carried across cc
  short8 aHc[2], aLc[2], bHc[8], bLc[8];
  #pragma unroll
  for (int i = 0; i < 2; ++i) {
    aHc[i] = *(const short8*)(Zl + (size_t)(i*16 + 0) * 1024);
    aLc[i] = *(const short8*)(Zl + (size_t)(i*16 + 8) * 1024);
  }
  #pragma unroll
  for (int jj = 0; jj < 8; ++jj) {
    bHc[jj] = *(const short8*)(ebase + (size_t)0 * 262144 + jj * 1024);
    bLc[jj] = *(const short8*)(ebase + (size_t)8 * 262144 + jj * 1024);
  }

  for (int cc = 0; cc < 16; ++cc) {              // 256-code chunks
    const char* ecc  = ebase + (size_t)cc * 16384;
    const char* eccn = ebase + (size_t)((cc + 1) & 15) * 16384;

    f32x4 acc[2][8];
    #pragma unroll
    for (int i = 0; i < 2; ++i)
      #pragma unroll
      for (int jj = 0; jj < 8; ++jj) acc[i][jj] = (f32x4){0.f,0.f,0.f,0.f};

    float e2v[8];
    #pragma unroll
    for (int jj = 0; jj < 8; ++jj)
      e2v[jj] = e2g[cc*256 + cg*128 + jj*16 + cl];

    #pragma unroll
    for (int kw = 0; kw < 8; ++kw) {
      // issue next step's loads (B global first, then A ds)
      short8 aHn[2], aLn[2], bHn[8], bLn[8];
      {
        const char* bsrc = (kw < 7) ? ecc : eccn;
        const int kwn = (kw + 1) & 7;
        #pragma unroll
        for (int jj = 0; jj < 8; ++jj) {
          bHn[jj] = *(const short8*)(bsrc + (size_t)(kwn    ) * 262144 + jj * 1024);
          bLn[jj] = *(const short8*)(bsrc + (size_t)(kwn + 8) * 262144 + jj * 1024);
        }
        #pragma unroll
        for (int i = 0; i < 2; ++i) {
          aHn[i] = *(const short8*)(Zl + (size_t)(i*16 + kwn    ) * 1024);
          aLn[i] = *(const short8*)(Zl + (size_t)(i*16 + kwn + 8) * 1024);
        }
      }
      __builtin_amdgcn_s_setprio(1);   // fence bounds hoist window (R15)
      #pragma unroll
      for (int i = 0; i < 2; ++i)
        #pragma unroll
        for (int jj = 0; jj < 8; ++jj)
          acc[i][jj] = __builtin_amdgcn_mfma_f32_16x16x32_bf16(aHc[i], bHc[jj], acc[i][jj], 0, 0, 0);
      #pragma unroll
      for (int i = 0; i < 2; ++i)
        #pragma unroll
        for (int jj = 0; jj < 8; ++jj)
          acc[i][jj] = __builtin_amdgcn_mfma_f32_16x16x32_bf16(aHc[i], bLc[jj], acc[i][jj], 0, 0, 0);
      #pragma unroll
      for (int i = 0; i < 2; ++i)
        #pragma unroll
        for (int jj = 0; jj < 8; ++jj)
          acc[i][jj] = __builtin_amdgcn_mfma_f32_16x16x32_bf16(aLc[i], bHc[jj], acc[i][jj], 0, 0, 0);
      __builtin_amdgcn_s_setprio(0);
      // rename pipeline regs
      #pragma unroll
      for (int i = 0; i < 2; ++i) { aHc[i] = aHn[i]; aLc[i] = aLn[i]; }
      #pragma unroll
      for (int jj = 0; jj < 8; ++jj) { bHc[jj] = bHn[jj]; bLc[jj] = bLn[jj]; }
    }
    // epilogue: scores -> running argmin (codes ascend: cc outer, jj inner)
    #pragma unroll
    for (int jj = 0; jj < 8; ++jj) {
      const int code = cc*256 + cg*128 + jj*16 + cl;
      #pragma unroll
      for (int i = 0; i < 2; ++i)
        #pragma unroll
        for (int r = 0; r < 4; ++r) {
          const float sc = e2v[jj] - 2.0f * acc[i][jj][r];
          if (sc < bestv[i][r]) { bestv[i][r] = sc; besti[i][r] = code; }
        }
    }
  }

  // ---- final argmin reduce: 16 code-lanes, then 2 cg waves via LDS ----
  struct RP { float v; int i; };
  RP*  red    = (RP*)(smem + 131072);          // [128][2]
  int* sh_idx = (int*)(smem + 131072 + 4096);  // [128]
  #pragma unroll
  for (int i = 0; i < 2; ++i)
    #pragma unroll
    for (int r = 0; r < 4; ++r) {
      float v = bestv[i][r]; int bi = besti[i][r];
      #pragma unroll
      for (int m = 1; m < 16; m <<= 1) {
        const float ov = __shfl_xor(v, m, 64);
        const int   oi = __shfl_xor(bi, m, 64);
        if (ov < v || (ov == v && oi < bi)) { v = ov; bi = oi; }
      }
      if (cl == 0) {                 // lanes 0,16,32,48 own token tg*32+i*16+g*4+r
        const int tl = tg*32 + i*16 + g*4 + r;
        red[tl*2 + cg].v = v; red[tl*2 + cg].i = bi;
      }
    }
  __syncthreads();
  if (tid < 128) {
    float v = red[tid*2].v; int bi = red[tid*2].i;
    {
      const float ov = red[tid*2 + 1].v; const int oi = red[tid*2 + 1].i;
      if (ov < v || (ov == v && oi < bi)) { v = ov; bi = oi; }
    }
    zidx_f[t0 + tid] = (float)bi;
    sh_idx[tid] = bi;
  }
  __syncthreads();

  // ---- fused gather: quant[t] = e[idx[t]] (f32, e is L2-resident) ----
  #pragma unroll
  for (int rr = 0; rr < 2; ++rr) {
    const int r   = rr*64 + (tid >> 3);    // token row 0..127
    const int cq  = (tid & 7) << 5;        // col base 0..224
    const int idx = sh_idx[r];
    #pragma unroll
    for (int it = 0; it < 4; ++it) {
      const float4 v0 = *(const float4*)&eg[(size_t)idx * CDIM + cq + it*8];
      const float4 v1 = *(const float4*)&eg[(size_t)idx * CDIM + cq + it*8 + 4];
      *(float4*)&quant[(size_t)(t0 + r) * CDIM + cq + it*8]     = v0;
      *(float4*)&quant[(size_t)(t0 + r) * CDIM + cq + it*8 + 4] = v1;
    }
  }
}

// ---------------- launch ----------------------------------------------------
extern "C" void kernel_launch(void* const* d_in, const int* in_sizes, int n_in,
                              void* d_out, int out_size, void* d_ws, size_t ws_size,
                              hipStream_t stream) {
  const float* encode = (const float*)d_in[0];
  const float* cb     = (const float*)d_in[1];
  const float* pw     = (const float*)d_in[2];
  const float* pb     = (const float*)d_in[3];

  float* e  = (float*)d_ws;                           // 4 MB
  float* e2 = e + (size_t)K_CODES * CDIM;             // 16 KB
  unsigned short* Ect = (unsigned short*)(e2 + K_CODES); // 4 MB fragment-linear

  float* out     = (float*)d_out;
  float* zidx_f  = out;
  float* quant_f = out + NTOK;

  (void)hipFuncSetAttribute((const void*)score_mfma,
                            hipFuncAttributeMaxDynamicSharedMemorySize, 135680);

  proj_gemm<<<dim3(CDIM/64, K_CODES/64), 256, 0, stream>>>(cb, pw, pb, e, Ect);
  compute_e2<<<(K_CODES*64)/256, 256, 0, stream>>>(e, e2);
  score_mfma<<<NTOK/128, 512, 135680, stream>>>(encode, Ect, e2, e, zidx_f, quant_f);
}

// Round 20
// 222.468 us; speedup vs baseline: 1.1684x; 1.1684x over previous
//
#include <hip/hip_runtime.h>
#include <hip/hip_bf16.h>

// QuantiZ: e = codebook[4096,1024] @ proj_w[256,1024]^T + proj_b
//          zidx[t] = argmin_k ||z_t - e_k||, quant[t] = e[zidx[t]]
// d_out FLOAT32: [ zidx as float (32768) | quant (32768*256) ].
// Score GEMM: split-bf16 3-term (hi*hi + hi*lo + lo*hi), 16x16x32 MFMA.
// R20: score_mfma = exact R18 (best: 175us; R19's jj=8 refuted - L1 cost
//      scales with requests). proj_gemm: 512 threads (2 waves/SIMD latency
//      hiding) + deterministic fused e2 partials; compute_e2 deleted.

#define K_CODES 4096
#define CDIM    256
#define IDIM    1024
#define NTOK    32768

typedef __attribute__((ext_vector_type(8))) short short8;
typedef __attribute__((ext_vector_type(4))) float f32x4;

__device__ __forceinline__ unsigned short f32_to_bf16_rne(float f) {
  union { float f; unsigned int u; } x; x.f = f;
  unsigned int r = x.u + 0x7FFFu + ((x.u >> 16) & 1u);
  return (unsigned short)(r >> 16);
}
__device__ __forceinline__ float bf16_to_f32(unsigned short h) {
  union { unsigned int u; float f; } x; x.u = ((unsigned int)h) << 16;
  return x.f;
}

// ---- Kernel A: e = cb @ pw^T + pb (f32 64x64 tile, 512 thr) + Ect + e2p ----
// LDS tiles k-major [32][68]; acc 2x4 per thread (ty 0..31 row-pairs).
// Ect layout: frag(kb 0..15, ct 0..255) = 1024 B at (kb*256+ct)*1024,
// lane lf = g*16 + cl holds k-octet g of code ct*16+cl; kb0-7 hi, 8-15 lo.
// e2p[chunk 0..3][row]: partial sum of e^2 over cols chunk*64..chunk*64+63.
extern "C" __global__ __launch_bounds__(512)
void proj_gemm(const float* __restrict__ cb, const float* __restrict__ pw,
               const float* __restrict__ pb, float* __restrict__ e,
               unsigned short* __restrict__ Ect, float* __restrict__ e2p) {
  __shared__ float As[32][68];   // [kk][row]
  __shared__ float Bs[32][68];
  const int tid = threadIdx.x;
  const int tx = tid & 15, ty = tid >> 4;   // ty 0..31
  const int m0 = blockIdx.y << 6;
  const int n0 = blockIdx.x << 6;
  const int r  = tid >> 3;                  // staging row 0..63
  const int c4 = (tid & 7) << 2;            // staging col 0,4,..,28
  float acc[2][4] = {};
  for (int k0 = 0; k0 < IDIM; k0 += 32) {
    float4 a0 = *(const float4*)&cb[(size_t)(m0 + r) * IDIM + k0 + c4];
    float4 b0 = *(const float4*)&pw[(size_t)(n0 + r) * IDIM + k0 + c4];
    __syncthreads();
    As[c4+0][r]=a0.x; As[c4+1][r]=a0.y; As[c4+2][r]=a0.z; As[c4+3][r]=a0.w;
    Bs[c4+0][r]=b0.x; Bs[c4+1][r]=b0.y; Bs[c4+2][r]=b0.z; Bs[c4+3][r]=b0.w;
    __syncthreads();
    #pragma unroll
    for (int kk = 0; kk < 32; ++kk) {
      const float2 av = *(const float2*)&As[kk][ty*2];
      const float4 bv = *(const float4*)&Bs[kk][tx*4];
      const float a2[2] = {av.x, av.y};
      const float b4[4] = {bv.x, bv.y, bv.z, bv.w};
      #pragma unroll
      for (int i = 0; i < 2; ++i)
        #pragma unroll
        for (int j = 0; j < 4; ++j)
          acc[i][j] += a2[i] * b4[j];
    }
  }
  // epilogue: write e (f32), fragment-linear hi/lo bf16 Ect, and e2 partials
  const int col0 = n0 + tx*4;
  const int kb   = col0 >> 5;
  const int g    = (col0 >> 3) & 3;
  const int half = (col0 >> 2) & 1;
  float p2[2];
  #pragma unroll
  for (int i = 0; i < 2; ++i) {
    const int row = m0 + ty*2 + i;
    float vv[4];
    unsigned short h4[4], l4[4];
    #pragma unroll
    for (int j = 0; j < 4; ++j) {
      vv[j] = acc[i][j] + pb[col0 + j];
      h4[j] = f32_to_bf16_rne(vv[j]);
      l4[j] = f32_to_bf16_rne(vv[j] - bf16_to_f32(h4[j]));
    }
    *(float4*)&e[(size_t)row * CDIM + col0] = *(float4*)vv;
    const int ct = row >> 4, cl = row & 15;
    const size_t fi = ((size_t)(kb      * 256 + ct) * 64 + g*16 + cl) * 8 + half*4;
    const size_t fo = ((size_t)((kb+8)  * 256 + ct) * 64 + g*16 + cl) * 8 + half*4;
    *(ushort4*)&Ect[fi] = *(ushort4*)h4;
    *(ushort4*)&Ect[fo] = *(ushort4*)l4;
    p2[i] = vv[0]*vv[0] + vv[1]*vv[1] + vv[2]*vv[2] + vv[3]*vv[3];
  }
  // deterministic 16-lane (tx) reduction of the two row-partials
  #pragma unroll
  for (int m = 1; m < 16; m <<= 1) {
    p2[0] += __shfl_xor(p2[0], m, 64);
    p2[1] += __shfl_xor(p2[1], m, 64);
  }
  if (tx == 0) {
    e2p[(size_t)blockIdx.x * K_CODES + m0 + ty*2    ] = p2[0];
    e2p[(size_t)blockIdx.x * K_CODES + m0 + ty*2 + 1] = p2[1];
  }
}

// ---------------- Kernel B: MFMA score + argmin + fused gather --------------
// (exact R18 structure) 128 tokens/block, 8 waves = 2 tg x 4 cg.
// Wave = 64 tok x 64 codes (i in 4, jj in 4). Z: 128 frag-linear LDS frags.
// e2 read as sum of 4 deterministic partials.
extern "C" __global__ __launch_bounds__(512, 2)
void score_mfma(const float* __restrict__ z, const unsigned short* __restrict__ Ect,
                const float* __restrict__ e2p, const float* __restrict__ eg,
                float* __restrict__ zidx_f, float* __restrict__ quant) {
  extern __shared__ __align__(16) char smem[];   // 128K Z + 4K red + 512 idx
  char* Zb = smem;

  const int tid = threadIdx.x;
  const int l   = tid & 63;
  const int w   = tid >> 6;          // wave 0..7
  const int tg  = w >> 2;            // token group 0..1
  const int cg  = w & 3;             // code group 0..3
  const int t0  = blockIdx.x << 7;   // 128 tokens per block

  // ---- stage Z (hi/lo bf16) into fragment-linear LDS frags ----
  #pragma unroll
  for (int rr = 0; rr < 2; ++rr) {
    const int r  = rr*64 + (tid >> 3);    // token row 0..127
    const int cq = tid & 7;               // col base cq*32
    const int i8 = r >> 4;                // frag i 0..7
    const int rl = (r & 15) << 4;         // lane-slot byte within frag
    #pragma unroll
    for (int it = 0; it < 4; ++it) {
      const int col = cq*32 + it*8;       // g = it, kb_hi = cq, kb_lo = cq+8
      const float4 v0 = *(const float4*)&z[(size_t)(t0 + r) * CDIM + col];
      const float4 v1 = *(const float4*)&z[(size_t)(t0 + r) * CDIM + col + 4];
      float vv[8] = {v0.x,v0.y,v0.z,v0.w,v1.x,v1.y,v1.z,v1.w};
      unsigned int hp[4], lp[4];
      #pragma unroll
      for (int c = 0; c < 4; ++c) {
        unsigned short h0 = f32_to_bf16_rne(vv[2*c]);
        unsigned short h1 = f32_to_bf16_rne(vv[2*c+1]);
        unsigned short l0 = f32_to_bf16_rne(vv[2*c]   - bf16_to_f32(h0));
        unsigned short l1 = f32_to_bf16_rne(vv[2*c+1] - bf16_to_f32(h1));
        hp[c] = (unsigned int)h0 | ((unsigned int)h1 << 16);
        lp[c] = (unsigned int)l0 | ((unsigned int)l1 << 16);
      }
      const int lane_b = it*256 + rl;     // (g*16 + (r&15)) * 16
      *(uint4*)(Zb + (size_t)(i8*16 + cq    ) * 1024 + lane_b) = *(uint4*)hp;
      *(uint4*)(Zb + (size_t)(i8*16 + cq + 8) * 1024 + lane_b) = *(uint4*)lp;
    }
  }
  __syncthreads();   // Z ready; no further barriers until final reduce

  float bestv[4][4];
  int   besti[4][4];
  #pragma unroll
  for (int i = 0; i < 4; ++i)
    #pragma unroll
    for (int r = 0; r < 4; ++r) { bestv[i][r] = 3.4e38f; besti[i][r] = 0; }

  const int cl = l & 15;
  const int g  = l >> 4;

  // Ect frag(kb, ct) at (kb*256+ct)*1024; wave's ct = cc*16 + cg*4 + jj
  const char* ebase = (const char*)Ect + (size_t)l * 16 + (size_t)cg * 4096;
  // A frags for this wave: frag index (tg*4 + i)*16 + kb
  const char* Zl    = Zb + (size_t)l * 16 + (size_t)tg * 65536;

  // pipeline registers (depth-1), carried across cc
  short8 aHc[4], aLc[4], bHc[4], bLc[4];
  #pragma unroll
  for (int i = 0; i < 4; ++i) {
    aHc[i] = *(const short8*)(Zl + (size_t)(i*16 + 0) * 1024);
    aLc[i] = *(const short8*)(Zl + (size_t)(i*16 + 8) * 1024);
  }
  #pragma unroll
  for (int jj = 0; jj < 4; ++jj) {
    bHc[jj] = *(const short8*)(ebase + (size_t)0 * 262144 + jj * 1024);
    bLc[jj] = *(const short8*)(ebase + (size_t)8 * 262144 + jj * 1024);
  }

  for (int cc = 0; cc < 16; ++cc) {              // 256-code chunks
    const char* ecc  = ebase + (size_t)cc * 16384;
    const char* eccn = ebase + (size_t)((cc + 1) & 15) * 16384;

    f32x4 acc[4][4];
    #pragma unroll
    for (int i = 0; i < 4; ++i)
      #pragma unroll
      for (int jj = 0; jj < 4; ++jj) acc[i][jj] = (f32x4){0.f,0.f,0.f,0.f};

    float e2v[4];
    #pragma unroll
    for (int jj = 0; jj < 4; ++jj) {
      const int code = cc*256 + cg*64 + jj*16 + cl;
      e2v[jj] = e2p[code] + e2p[K_CODES + code]
              + e2p[2*K_CODES + code] + e2p[3*K_CODES + code];
    }

    #pragma unroll
    for (int kw = 0; kw < 8; ++kw) {
      // issue next step's loads (B global first, then A ds)
      short8 aHn[4], aLn[4], bHn[4], bLn[4];
      {
        const char* bsrc = (kw < 7) ? ecc : eccn;
        const int kwn = (kw + 1) & 7;
        #pragma unroll
        for (int jj = 0; jj < 4; ++jj) {
          bHn[jj] = *(const short8*)(bsrc + (size_t)(kwn    ) * 262144 + jj * 1024);
          bLn[jj] = *(const short8*)(bsrc + (size_t)(kwn + 8) * 262144 + jj * 1024);
        }
        #pragma unroll
        for (int i = 0; i < 4; ++i) {
          aHn[i] = *(const short8*)(Zl + (size_t)(i*16 + kwn    ) * 1024);
          aLn[i] = *(const short8*)(Zl + (size_t)(i*16 + kwn + 8) * 1024);
        }
      }
      __builtin_amdgcn_s_setprio(1);   // fence bounds hoist window (R15)
      #pragma unroll
      for (int i = 0; i < 4; ++i)
        #pragma unroll
        for (int jj = 0; jj < 4; ++jj)
          acc[i][jj] = __builtin_amdgcn_mfma_f32_16x16x32_bf16(aHc[i], bHc[jj], acc[i][jj], 0, 0, 0);
      #pragma unroll
      for (int i = 0; i < 4; ++i)
        #pragma unroll
        for (int jj = 0; jj < 4; ++jj)
          acc[i][jj] = __builtin_amdgcn_mfma_f32_16x16x32_bf16(aHc[i], bLc[jj], acc[i][jj], 0, 0, 0);
      #pragma unroll
      for (int i = 0; i < 4; ++i)
        #pragma unroll
        for (int jj = 0; jj < 4; ++jj)
          acc[i][jj] = __builtin_amdgcn_mfma_f32_16x16x32_bf16(aLc[i], bHc[jj], acc[i][jj], 0, 0, 0);
      __builtin_amdgcn_s_setprio(0);
      // rename pipeline regs
      #pragma unroll
      for (int i = 0; i < 4; ++i) { aHc[i] = aHn[i]; aLc[i] = aLn[i]; }
      #pragma unroll
      for (int jj = 0; jj < 4; ++jj) { bHc[jj] = bHn[jj]; bLc[jj] = bLn[jj]; }
    }
    // epilogue: scores -> running argmin (codes ascend: cc outer, jj inner)
    #pragma unroll
    for (int jj = 0; jj < 4; ++jj) {
      const int code = cc*256 + cg*64 + jj*16 + cl;
      #pragma unroll
      for (int i = 0; i < 4; ++i)
        #pragma unroll
        for (int r = 0; r < 4; ++r) {
          const float sc = e2v[jj] - 2.0f * acc[i][jj][r];
          if (sc < bestv[i][r]) { bestv[i][r] = sc; besti[i][r] = code; }
        }
    }
  }

  // ---- final argmin reduce: 16 code-lanes, then 4 cg waves via LDS ----
  struct RP { float v; int i; };
  RP*  red    = (RP*)(smem + 131072);          // [128][4]
  int* sh_idx = (int*)(smem + 131072 + 4096);  // [128]
  #pragma unroll
  for (int i = 0; i < 4; ++i)
    #pragma unroll
    for (int r = 0; r < 4; ++r) {
      float v = bestv[i][r]; int bi = besti[i][r];
      #pragma unroll
      for (int m = 1; m < 16; m <<= 1) {
        const float ov = __shfl_xor(v, m, 64);
        const int   oi = __shfl_xor(bi, m, 64);
        if (ov < v || (ov == v && oi < bi)) { v = ov; bi = oi; }
      }
      if (cl == 0) {                 // lanes 0,16,32,48 own token tg*64+i*16+g*4+r
        const int tl = tg*64 + i*16 + g*4 + r;
        red[tl*4 + cg].v = v; red[tl*4 + cg].i = bi;
      }
    }
  __syncthreads();
  if (tid < 128) {
    float v = red[tid*4].v; int bi = red[tid*4].i;
    #pragma unroll
    for (int x = 1; x < 4; ++x) {
      const float ov = red[tid*4 + x].v; const int oi = red[tid*4 + x].i;
      if (ov < v || (ov == v && oi < bi)) { v = ov; bi = oi; }
    }
    zidx_f[t0 + tid] = (float)bi;
    sh_idx[tid] = bi;
  }
  __syncthreads();

  // ---- fused gather: quant[t] = e[idx[t]] (f32, e is L2-resident) ----
  #pragma unroll
  for (int rr = 0; rr < 2; ++rr) {
    const int r   = rr*64 + (tid >> 3);    // token row 0..127
    const int cq  = (tid & 7) << 5;        // col base 0..224
    const int idx = sh_idx[r];
    #pragma unroll
    for (int it = 0; it < 4; ++it) {
      const float4 v0 = *(const float4*)&eg[(size_t)idx * CDIM + cq + it*8];
      const float4 v1 = *(const float4*)&eg[(size_t)idx * CDIM + cq + it*8 + 4];
      *(float4*)&quant[(size_t)(t0 + r) * CDIM + cq + it*8]     = v0;
      *(float4*)&quant[(size_t)(t0 + r) * CDIM + cq + it*8 + 4] = v1;
    }
  }
}

// ---------------- launch ----------------------------------------------------
extern "C" void kernel_launch(void* const* d_in, const int* in_sizes, int n_in,
                              void* d_out, int out_size, void* d_ws, size_t ws_size,
                              hipStream_t stream) {
  const float* encode = (const float*)d_in[0];
  const float* cb     = (const float*)d_in[1];
  const float* pw     = (const float*)d_in[2];
  const float* pb     = (const float*)d_in[3];

  float* e   = (float*)d_ws;                              // 4 MB
  float* e2p = e + (size_t)K_CODES * CDIM;                // 64 KB (4 partials)
  unsigned short* Ect = (unsigned short*)(e2p + 4*K_CODES); // 4 MB frag-linear

  float* out     = (float*)d_out;
  float* zidx_f  = out;
  float* quant_f = out + NTOK;

  (void)hipFuncSetAttribute((const void*)score_mfma,
                            hipFuncAttributeMaxDynamicSharedMemorySize, 135680);

  proj_gemm<<<dim3(CDIM/64, K_CODES/64), 512, 0, stream>>>(cb, pw, pb, e, Ect, e2p);
  score_mfma<<<NTOK/128, 512, 135680, stream>>>(encode, Ect, e2p, e, zidx_f, quant_f);
}